// Round 6
// baseline (3467.204 us; speedup 1.0000x reference)
//
#include <hip/hip_runtime.h>
#include <math.h>

// ---------------------------------------------------------------------------
// MultiModalImputer forward.
// R6 change: scan back to R4's LDS-broadcast reads (readlane hazard killed
// R5), but 2 output columns per thread (j, j+288) at 320 threads/block with
// __launch_bounds__(320,2): 192 weight-VGPRs fit under the 256 cap, and
// per-CU LDS instrs/step drop 216 -> 120 (the R4 bottleneck).
// ---------------------------------------------------------------------------

constexpr int N_   = 16;
constexpr int L_   = 1024;
constexpr int D_   = 12;
constexpr int E_   = 8;
constexpr int HID_ = 16;
constexpr int ADM_ = 64;
constexpr int H_   = 192;   // HID*D
constexpr int H3_  = 576;   // 3*H
constexpr int IN0_ = 96;    // D*E
constexpr int IN1_ = 384;   // 2*H
constexpr int NL_  = N_ * L_;  // 16384
constexpr int FFH_ = 512;

#define F4(p) (*(const float4*)(p))

typedef _Float16 half2v __attribute__((ext_vector_type(2)));
union U32H2 { unsigned int u; half2v h; };
union H16U { _Float16 f; unsigned short s; };

__device__ __forceinline__ float dot2acc(unsigned int wu, unsigned int hu, float acc) {
#if __has_builtin(__builtin_amdgcn_fdot2)
  U32H2 a, b; a.u = wu; b.u = hu;
  return __builtin_amdgcn_fdot2(a.h, b.h, acc, false);
#else
  U32H2 a, b; a.u = wu; b.u = hu;
  acc = fmaf((float)a.h.x, (float)b.h.x, acc);
  return fmaf((float)a.h.y, (float)b.h.y, acc);
#endif
}

// ---------------- K1: adm MLP: relu(adm@W1.T+b1)@W2.T+b2 -> [16,16] --------
__global__ void adm_mlp_kernel(const float* __restrict__ adm,
                               const float* __restrict__ W1, const float* __restrict__ b1,
                               const float* __restrict__ W2, const float* __restrict__ b2,
                               float* __restrict__ adm_out) {
  __shared__ float hid[N_][HID_];
  const int t = threadIdx.x;        // 256
  const int n = t >> 4, j = t & 15;
  float acc = b1[j];
  for (int k = 0; k < ADM_; ++k) acc = fmaf(adm[n * ADM_ + k], W1[j * ADM_ + k], acc);
  hid[n][j] = fmaxf(acc, 0.f);
  __syncthreads();
  float acc2 = b2[j];
  for (int k = 0; k < HID_; ++k) acc2 = fmaf(hid[n][k], W2[j * HID_ + k], acc2);
  adm_out[n * HID_ + j] = acc2;
}

// ---------------- K2: fused mask-embedding + per-channel Linear(1->8) ------
__global__ void embed_kernel(const float* __restrict__ series, const int* __restrict__ mask,
                             const float* __restrict__ sW, const float* __restrict__ membW,
                             float* __restrict__ emb) {
  const int i = blockIdx.x * blockDim.x + threadIdx.x;   // over NL*96
  if (i >= NL_ * IN0_) return;
  const int de = i % IN0_;
  const int nl = i / IN0_;
  const int d = de >> 3, e = de & 7;
  const float s = series[nl * D_ + d];
  const int   m = mask[nl * D_ + d];
  const int idx = m ? (d + 1) : 0;
  emb[i] = membW[idx * E_ + e] + s * sW[de];
}

// ------- K3: pack Whh [576][192] f32 -> [24][576][4] uint32 (f16 pairs) ----
// out[((kc*576 + j)*4 + c)] packs k = kc*8 + c*2 and k+1 of row j.
__global__ void whh_pack16_kernel(const float* __restrict__ Whh, unsigned int* __restrict__ Wp) {
  const int o = blockIdx.x * blockDim.x + threadIdx.x;   // 576*96 = 55296
  if (o >= H3_ * 96) return;
  const int c  = o & 3;
  const int j  = (o >> 2) % H3_;
  const int kc = (o >> 2) / H3_;
  const int k  = kc * 8 + c * 2;
  H16U lo, hi;
  lo.f = (_Float16)Whh[j * H_ + k];
  hi.f = (_Float16)Whh[j * H_ + k + 1];
  Wp[o] = (unsigned int)lo.s | ((unsigned int)hi.s << 16);
}

// ---------------- K4: xp GEMM: xp[dir][row][j] = A@W^T + bih ---------------
// A [NL][K] row-major, Wf/Wb [576][K] row-major. BM=BN=128, BK=16, 8x8/thread.
__global__ __launch_bounds__(256)
void xp_gemm_kernel(const float* __restrict__ A, const int K,
                    const float* __restrict__ Wf, const float* __restrict__ Wb,
                    const float* __restrict__ bf, const float* __restrict__ bb,
                    float* __restrict__ xp /* [2][NL][576] */) {
  constexpr int BM = 128, BN = 128, BK = 16, TM = 8, TN = 8;
  __shared__ float As[BK][BM + 4];
  __shared__ float Bs[BK][BN + 4];
  const int bm = blockIdx.x;   // 128
  const int bn = blockIdx.y;   // 9
  const int t = threadIdx.x;
  const int tx = t & 15, ty = t >> 4;
  const int row0 = bm * BM, col0 = bn * BN;
  float acc[TM][TN] = {};

  for (int k0 = 0; k0 < K; k0 += BK) {
    #pragma unroll
    for (int r = 0; r < 2; ++r) {
      const int li = t + r * 256;
      const int i = li >> 2;
      const int kc = (li & 3) << 2;
      float4 v = F4(A + (size_t)(row0 + i) * K + k0 + kc);
      As[kc + 0][i] = v.x; As[kc + 1][i] = v.y; As[kc + 2][i] = v.z; As[kc + 3][i] = v.w;
    }
    #pragma unroll
    for (int r = 0; r < 2; ++r) {
      const int li = t + r * 256;
      const int jj = li >> 2;
      const int kc = (li & 3) << 2;
      const int col = col0 + jj;
      const float* W = (col < H3_) ? Wf : Wb;
      const int wrow = (col < H3_) ? col : col - H3_;
      float4 v = F4(W + (size_t)wrow * K + k0 + kc);
      Bs[kc + 0][jj] = v.x; Bs[kc + 1][jj] = v.y; Bs[kc + 2][jj] = v.z; Bs[kc + 3][jj] = v.w;
    }
    __syncthreads();
    #pragma unroll
    for (int kk = 0; kk < BK; ++kk) {
      float a[TM], b[TN];
      const float4* a4 = (const float4*)&As[kk][ty * TM];
      const float4* b4 = (const float4*)&Bs[kk][tx * TN];
      float4 av0 = a4[0], av1 = a4[1], bv0 = b4[0], bv1 = b4[1];
      a[0]=av0.x; a[1]=av0.y; a[2]=av0.z; a[3]=av0.w; a[4]=av1.x; a[5]=av1.y; a[6]=av1.z; a[7]=av1.w;
      b[0]=bv0.x; b[1]=bv0.y; b[2]=bv0.z; b[3]=bv0.w; b[4]=bv1.x; b[5]=bv1.y; b[6]=bv1.z; b[7]=bv1.w;
      #pragma unroll
      for (int i = 0; i < TM; ++i)
        #pragma unroll
        for (int jq = 0; jq < TN; ++jq) acc[i][jq] = fmaf(a[i], b[jq], acc[i][jq]);
    }
    __syncthreads();
  }
  #pragma unroll
  for (int i = 0; i < TM; ++i) {
    const int row = row0 + ty * TM + i;
    #pragma unroll
    for (int jq = 0; jq < TN; ++jq) {
      const int col = col0 + tx * TN + jq;
      const int dir = (col >= H3_);
      const int jj = col - dir * H3_;
      const float bias = dir ? bb[jj] : bf[jj];
      xp[((size_t)dir * NL_ + row) * H3_ + jj] = acc[i][jq] + bias;
    }
  }
}

// ---------------- K5: GRU scan. One block per (dir, batch). 320 threads. ---
// Thread j < 288 owns output cols j and j+288; f16-packed weight rows for
// both cols in VGPRs (192); h broadcast via ds_read_b128 (24/thread/step).
__global__ __launch_bounds__(320, 2)
void gru_scan_kernel(const float* __restrict__ xp,            // [2][NL][576]
                     const unsigned int* __restrict__ Wpf,    // [24][576][4] f16-pairs
                     const unsigned int* __restrict__ Wpb,
                     const float* __restrict__ bhf,
                     const float* __restrict__ bhb,
                     float* __restrict__ hcat) {              // [NL][384]
  const int dir = blockIdx.x >> 4;
  const int n   = blockIdx.x & 15;
  const float* __restrict__ xpd = xp + ((size_t)dir * NL_ + (size_t)n * L_) * H3_;
  const unsigned int* __restrict__ Wp = dir ? Wpb : Wpf;
  const float* __restrict__ bh  = dir ? bhb : bhf;
  float* __restrict__ outd = hcat + (size_t)n * L_ * IN1_ + dir * H_;

  const int j  = threadIdx.x;            // 0..319; active j < 288
  const int j2 = j + 288;
  const bool act = (j < 288);

  __shared__ __align__(16) unsigned int h16[128];  // 96 used (192 f16), padded
  __shared__ float gh_lds[H3_];
  __shared__ float xn_lds[H_];

  // f16-packed weight rows j and j+288: 2 x 24 uint4 = 192 VGPRs
  uint4 w1[24], w2[24];
  if (act) {
    #pragma unroll
    for (int kc = 0; kc < 24; ++kc) {
      w1[kc] = ((const uint4*)Wp)[kc * H3_ + j];
      w2[kc] = ((const uint4*)Wp)[kc * H3_ + j2];
    }
  }
  const float bj1 = act ? bh[j]  : 0.f;
  const float bj2 = act ? bh[j2] : 0.f;
  if (j < 128) h16[j] = 0u;
  float hprev = 0.f;                       // valid for j < H_
  __syncthreads();

  const uint4* __restrict__ h4 = (const uint4*)h16;
  const int ts = dir ? -1 : 1;
  int t = dir ? (L_ - 1) : 0;
  float xv1 = 0.f, xv2 = 0.f;
  if (act) { xv1 = xpd[(size_t)t * H3_ + j]; xv2 = xpd[(size_t)t * H3_ + j2]; }

  for (int tt = 0; tt < L_; ++tt) {
    float xn1 = 0.f, xn2 = 0.f;
    if (act && tt + 1 < L_) {
      xn1 = xpd[(size_t)(t + ts) * H3_ + j];
      xn2 = xpd[(size_t)(t + ts) * H3_ + j2];
    }

    if (act) {
      float a0 = bj1, a1 = 0.f, a2 = 0.f, a3 = 0.f;
      float c0 = bj2, c1 = 0.f, c2 = 0.f, c3 = 0.f;
      #pragma unroll
      for (int kc = 0; kc < 24; ++kc) {
        uint4 hv = h4[kc];                 // broadcast: same addr across wave
        a0 = dot2acc(w1[kc].x, hv.x, a0);
        a1 = dot2acc(w1[kc].y, hv.y, a1);
        a2 = dot2acc(w1[kc].z, hv.z, a2);
        a3 = dot2acc(w1[kc].w, hv.w, a3);
        c0 = dot2acc(w2[kc].x, hv.x, c0);
        c1 = dot2acc(w2[kc].y, hv.y, c1);
        c2 = dot2acc(w2[kc].z, hv.z, c2);
        c3 = dot2acc(w2[kc].w, hv.w, c3);
      }
      float acc1 = (a0 + a1) + (a2 + a3);
      float acc2 = (c0 + c1) + (c2 + c3);

      gh_lds[j] = acc1 + xv1;              // j < 288 < 2H: always add xv
      if (j < 96) {                        // j2 < 384: z-gate col
        gh_lds[j2] = acc2 + xv2;
      } else {                             // j2 >= 384: n-gate col
        gh_lds[j2] = acc2;
        xn_lds[j2 - 2 * H_] = xv2;
      }
    }
    __syncthreads();

    if (j < H_) {
      const float r  = 1.f / (1.f + __expf(-gh_lds[j]));
      const float z  = 1.f / (1.f + __expf(-gh_lds[H_ + j]));
      const float nn = tanhf(xn_lds[j] + r * gh_lds[2 * H_ + j]);
      const float hnew = (1.f - z) * nn + z * hprev;
      hprev = hnew;
      H16U cv; cv.f = (_Float16)hnew;
      ((unsigned short*)h16)[j] = cv.s;    // ds_write_b16
      outd[(size_t)t * IN1_ + j] = hnew;
    }
    __syncthreads();

    xv1 = xn1; xv2 = xn2;
    t += ts;
  }
}

// ---------------- K6: fused per-channel FFN + LayerNorm + ReLU + Linear ----
// Block: (d, 128 rows). 256 threads; thread owns W1 rows t and t+256 in regs.
__global__ __launch_bounds__(256)
void ffn_kernel(const float* __restrict__ hcat, const float* __restrict__ adm_out,
                const float* __restrict__ W1, const float* __restrict__ b1,
                const float* __restrict__ lng, const float* __restrict__ lnb,
                const float* __restrict__ W2, const float* __restrict__ b2,
                float* __restrict__ out) {
  constexpr int FROWS = 8;
  const int d = blockIdx.y;            // 12
  const int row_base = blockIdx.x * 128;
  const int t = threadIdx.x;
  const int lane = t & 63, w = t >> 6;

  __shared__ __align__(16) float featL[FROWS][48];
  __shared__ __align__(16) float hhL[FROWS][FFH_];
  __shared__ float gL[FFH_], bLn[FFH_], w2L[FFH_], b1L[FFH_];

  for (int i = t; i < FFH_; i += 256) {
    gL[i]  = lng[d * FFH_ + i];
    bLn[i] = lnb[d * FFH_ + i];
    w2L[i] = W2[d * FFH_ + i];
    b1L[i] = b1[d * FFH_ + i];
  }
  float w1a[48], w1b[48];
  {
    const float* ra = W1 + ((size_t)d * FFH_ + t) * 48;
    const float* rb = W1 + ((size_t)d * FFH_ + 256 + t) * 48;
    #pragma unroll
    for (int kc = 0; kc < 12; ++kc) {
      float4 va = F4(ra + kc * 4);
      w1a[4*kc+0]=va.x; w1a[4*kc+1]=va.y; w1a[4*kc+2]=va.z; w1a[4*kc+3]=va.w;
      float4 vb = F4(rb + kc * 4);
      w1b[4*kc+0]=vb.x; w1b[4*kc+1]=vb.y; w1b[4*kc+2]=vb.z; w1b[4*kc+3]=vb.w;
    }
  }
  const float b2v = b2[d];
  __syncthreads();

  for (int c0 = 0; c0 < 128; c0 += FROWS) {
    for (int idx = t; idx < FROWS * 48; idx += 256) {
      const int r = idx / 48, k = idx % 48;
      const int row = row_base + c0 + r;
      float v;
      if (k < 32) v = hcat[(size_t)row * IN1_ + d * 32 + k];
      else        v = adm_out[(row >> 10) * HID_ + (k - 32)];
      featL[r][k] = v;
    }
    __syncthreads();
    float acc_a[FROWS] = {}, acc_b[FROWS] = {};
    #pragma unroll
    for (int r = 0; r < FROWS; ++r) {
      const float4* f4 = (const float4*)featL[r];
      #pragma unroll
      for (int kc = 0; kc < 12; ++kc) {
        float4 f = f4[kc];
        acc_a[r] = fmaf(w1a[4*kc+0], f.x, acc_a[r]);
        acc_a[r] = fmaf(w1a[4*kc+1], f.y, acc_a[r]);
        acc_a[r] = fmaf(w1a[4*kc+2], f.z, acc_a[r]);
        acc_a[r] = fmaf(w1a[4*kc+3], f.w, acc_a[r]);
        acc_b[r] = fmaf(w1b[4*kc+0], f.x, acc_b[r]);
        acc_b[r] = fmaf(w1b[4*kc+1], f.y, acc_b[r]);
        acc_b[r] = fmaf(w1b[4*kc+2], f.z, acc_b[r]);
        acc_b[r] = fmaf(w1b[4*kc+3], f.w, acc_b[r]);
      }
    }
    #pragma unroll
    for (int r = 0; r < FROWS; ++r) {
      hhL[r][t]       = acc_a[r] + b1L[t];
      hhL[r][t + 256] = acc_b[r] + b1L[t + 256];
    }
    __syncthreads();
    // LayerNorm + ReLU + W2 reduce: wave w handles rows w and w+4
    #pragma unroll
    for (int rr = 0; rr < 2; ++rr) {
      const int r = w + rr * 4;
      const float4* h4 = (const float4*)hhL[r];
      float4 x0 = h4[lane * 2], x1 = h4[lane * 2 + 1];
      float s = x0.x + x0.y + x0.z + x0.w + x1.x + x1.y + x1.z + x1.w;
      float q = x0.x*x0.x + x0.y*x0.y + x0.z*x0.z + x0.w*x0.w
              + x1.x*x1.x + x1.y*x1.y + x1.z*x1.z + x1.w*x1.w;
      #pragma unroll
      for (int m = 1; m < 64; m <<= 1) { s += __shfl_xor(s, m); q += __shfl_xor(q, m); }
      const float mu   = s * (1.f / FFH_);
      const float var  = q * (1.f / FFH_) - mu * mu;
      const float rstd = rsqrtf(var + 1e-5f);
      const int col = lane * 8;
      const float xs[8] = {x0.x, x0.y, x0.z, x0.w, x1.x, x1.y, x1.z, x1.w};
      float o = 0.f;
      #pragma unroll
      for (int i = 0; i < 8; ++i) {
        float v = (xs[i] - mu) * rstd * gL[col + i] + bLn[col + i];
        v = fmaxf(v, 0.f);
        o = fmaf(v, w2L[col + i], o);
      }
      #pragma unroll
      for (int m = 1; m < 64; m <<= 1) o += __shfl_xor(o, m);
      if (lane == 0) {
        const int row = row_base + c0 + r;
        out[(size_t)row * D_ + d] = o + b2v;
      }
    }
    __syncthreads();
  }
}

// ---------------------------------------------------------------------------
extern "C" void kernel_launch(void* const* d_in, const int* in_sizes, int n_in,
                              void* d_out, int out_size, void* d_ws, size_t ws_size,
                              hipStream_t stream) {
  const float* series = (const float*)d_in[0];
  const float* adm    = (const float*)d_in[1];
  const int*   mask   = (const int*)  d_in[2];
  const float* sW     = (const float*)d_in[3];
  const float* membW  = (const float*)d_in[4];
  const float* aW1    = (const float*)d_in[5];
  const float* ab1    = (const float*)d_in[6];
  const float* aW2    = (const float*)d_in[7];
  const float* ab2    = (const float*)d_in[8];
  const float* Wih0f  = (const float*)d_in[9];
  const float* Whh0f  = (const float*)d_in[10];
  const float* bih0f  = (const float*)d_in[11];
  const float* bhh0f  = (const float*)d_in[12];
  const float* Wih0b  = (const float*)d_in[13];
  const float* Whh0b  = (const float*)d_in[14];
  const float* bih0b  = (const float*)d_in[15];
  const float* bhh0b  = (const float*)d_in[16];
  const float* Wih1f  = (const float*)d_in[17];
  const float* Whh1f  = (const float*)d_in[18];
  const float* bih1f  = (const float*)d_in[19];
  const float* bhh1f  = (const float*)d_in[20];
  const float* Wih1b  = (const float*)d_in[21];
  const float* Whh1b  = (const float*)d_in[22];
  const float* bih1b  = (const float*)d_in[23];
  const float* bhh1b  = (const float*)d_in[24];
  const float* ffnW1  = (const float*)d_in[25];
  const float* ffnb1  = (const float*)d_in[26];
  const float* lng    = (const float*)d_in[27];
  const float* lnb    = (const float*)d_in[28];
  const float* ffnW2  = (const float*)d_in[29];
  const float* ffnb2  = (const float*)d_in[30];
  float* outp = (float*)d_out;

  // workspace layout (floats)
  float* ws      = (float*)d_ws;
  float* adm_out = ws;                                   // 256
  float* emb     = adm_out + 256;                        // NL*96   = 1,572,864
  float* xp      = emb + (size_t)NL_ * IN0_;             // 2*NL*576= 18,874,368
  float* hcat    = xp + (size_t)2 * NL_ * H3_;           // NL*384  = 6,291,456
  unsigned int* wp0f = (unsigned int*)(hcat + (size_t)NL_ * IN1_);  // 55,296 u32 each
  unsigned int* wp0b = wp0f + (size_t)H3_ * 96;
  unsigned int* wp1f = wp0b + (size_t)H3_ * 96;
  unsigned int* wp1b = wp1f + (size_t)H3_ * 96;

  adm_mlp_kernel<<<1, 256, 0, stream>>>(adm, aW1, ab1, aW2, ab2, adm_out);
  embed_kernel<<<(NL_ * IN0_) / 256, 256, 0, stream>>>(series, mask, sW, membW, emb);
  whh_pack16_kernel<<<(H3_ * 96) / 256, 256, 0, stream>>>(Whh0f, wp0f);
  whh_pack16_kernel<<<(H3_ * 96) / 256, 256, 0, stream>>>(Whh0b, wp0b);
  whh_pack16_kernel<<<(H3_ * 96) / 256, 256, 0, stream>>>(Whh1f, wp1f);
  whh_pack16_kernel<<<(H3_ * 96) / 256, 256, 0, stream>>>(Whh1b, wp1b);

  // layer 0
  xp_gemm_kernel<<<dim3(NL_ / 128, (2 * H3_) / 128), 256, 0, stream>>>(
      emb, IN0_, Wih0f, Wih0b, bih0f, bih0b, xp);
  gru_scan_kernel<<<32, 320, 0, stream>>>(xp, wp0f, wp0b, bhh0f, bhh0b, hcat);

  // layer 1 (xp buffer reused; hcat overwritten in place by scan output)
  xp_gemm_kernel<<<dim3(NL_ / 128, (2 * H3_) / 128), 256, 0, stream>>>(
      hcat, IN1_, Wih1f, Wih1b, bih1f, bih1b, xp);
  gru_scan_kernel<<<32, 320, 0, stream>>>(xp, wp1f, wp1b, bhh1f, bhh1b, hcat);

  // fused FFN
  ffn_kernel<<<dim3(NL_ / 128, D_), 256, 0, stream>>>(
      hcat, adm_out, ffnW1, ffnb1, lng, lnb, ffnW2, ffnb2, outp);
}

// Round 7
// 3433.767 us; speedup vs baseline: 1.0097x; 1.0097x over previous
//
#include <hip/hip_runtime.h>
#include <math.h>

// ---------------------------------------------------------------------------
// MultiModalImputer forward.
// R7 change (scan only; rest identical to R4 = 2691us best): h-broadcast via
// DPP quad_perm. Each lane ds_reads only its quarter of h (6xb128 = 96B,
// was 24xb128 = 384B), then v_mov_dpp broadcasts quarters within each quad
// (VALU pipe, not LDS, no SGPR-write hazard like R5's readlane).
// LDS/CU/step: 216->54 b128. New limiter: VALU ~900cy/step (was LDS 2477).
// ---------------------------------------------------------------------------

constexpr int N_   = 16;
constexpr int L_   = 1024;
constexpr int D_   = 12;
constexpr int E_   = 8;
constexpr int HID_ = 16;
constexpr int ADM_ = 64;
constexpr int H_   = 192;   // HID*D
constexpr int H3_  = 576;   // 3*H
constexpr int IN0_ = 96;    // D*E
constexpr int IN1_ = 384;   // 2*H
constexpr int NL_  = N_ * L_;  // 16384
constexpr int FFH_ = 512;

#define F4(p) (*(const float4*)(p))

typedef _Float16 half2v __attribute__((ext_vector_type(2)));
union U32H2 { unsigned int u; half2v h; };
union H16U { _Float16 f; unsigned short s; };

__device__ __forceinline__ float dot2acc(unsigned int wu, unsigned int hu, float acc) {
#if __has_builtin(__builtin_amdgcn_fdot2)
  U32H2 a, b; a.u = wu; b.u = hu;
  return __builtin_amdgcn_fdot2(a.h, b.h, acc, false);
#else
  U32H2 a, b; a.u = wu; b.u = hu;
  acc = fmaf((float)a.h.x, (float)b.h.x, acc);
  return fmaf((float)a.h.y, (float)b.h.y, acc);
#endif
}

// broadcast the register value held by lane R of each 4-lane quad
template<int R>
__device__ __forceinline__ unsigned int qbcast(unsigned int v) {
  constexpr int ctrl = R | (R << 2) | (R << 4) | (R << 6);   // quad_perm [R,R,R,R]
  return (unsigned int)__builtin_amdgcn_mov_dpp((int)v, ctrl, 0xF, 0xF, false);
}

// ---------------- K1: adm MLP: relu(adm@W1.T+b1)@W2.T+b2 -> [16,16] --------
__global__ void adm_mlp_kernel(const float* __restrict__ adm,
                               const float* __restrict__ W1, const float* __restrict__ b1,
                               const float* __restrict__ W2, const float* __restrict__ b2,
                               float* __restrict__ adm_out) {
  __shared__ float hid[N_][HID_];
  const int t = threadIdx.x;        // 256
  const int n = t >> 4, j = t & 15;
  float acc = b1[j];
  for (int k = 0; k < ADM_; ++k) acc = fmaf(adm[n * ADM_ + k], W1[j * ADM_ + k], acc);
  hid[n][j] = fmaxf(acc, 0.f);
  __syncthreads();
  float acc2 = b2[j];
  for (int k = 0; k < HID_; ++k) acc2 = fmaf(hid[n][k], W2[j * HID_ + k], acc2);
  adm_out[n * HID_ + j] = acc2;
}

// ---------------- K2: fused mask-embedding + per-channel Linear(1->8) ------
__global__ void embed_kernel(const float* __restrict__ series, const int* __restrict__ mask,
                             const float* __restrict__ sW, const float* __restrict__ membW,
                             float* __restrict__ emb) {
  const int i = blockIdx.x * blockDim.x + threadIdx.x;   // over NL*96
  if (i >= NL_ * IN0_) return;
  const int de = i % IN0_;
  const int nl = i / IN0_;
  const int d = de >> 3, e = de & 7;
  const float s = series[nl * D_ + d];
  const int   m = mask[nl * D_ + d];
  const int idx = m ? (d + 1) : 0;
  emb[i] = membW[idx * E_ + e] + s * sW[de];
}

// ------- K3: pack Whh [576][192] f32 -> [24][576][4] uint32 (f16 pairs) ----
// out[((kc*576 + j)*4 + c)] packs k = kc*8 + c*2 and k+1 of row j.
__global__ void whh_pack16_kernel(const float* __restrict__ Whh, unsigned int* __restrict__ Wp) {
  const int o = blockIdx.x * blockDim.x + threadIdx.x;   // 576*96 = 55296
  if (o >= H3_ * 96) return;
  const int c  = o & 3;
  const int j  = (o >> 2) % H3_;
  const int kc = (o >> 2) / H3_;
  const int k  = kc * 8 + c * 2;
  H16U lo, hi;
  lo.f = (_Float16)Whh[j * H_ + k];
  hi.f = (_Float16)Whh[j * H_ + k + 1];
  Wp[o] = (unsigned int)lo.s | ((unsigned int)hi.s << 16);
}

// ---------------- K4: xp GEMM: xp[dir][row][j] = A@W^T + bih ---------------
// A [NL][K] row-major, Wf/Wb [576][K] row-major. BM=BN=128, BK=16, 8x8/thread.
__global__ __launch_bounds__(256)
void xp_gemm_kernel(const float* __restrict__ A, const int K,
                    const float* __restrict__ Wf, const float* __restrict__ Wb,
                    const float* __restrict__ bf, const float* __restrict__ bb,
                    float* __restrict__ xp /* [2][NL][576] */) {
  constexpr int BM = 128, BN = 128, BK = 16, TM = 8, TN = 8;
  __shared__ float As[BK][BM + 4];
  __shared__ float Bs[BK][BN + 4];
  const int bm = blockIdx.x;   // 128
  const int bn = blockIdx.y;   // 9
  const int t = threadIdx.x;
  const int tx = t & 15, ty = t >> 4;
  const int row0 = bm * BM, col0 = bn * BN;
  float acc[TM][TN] = {};

  for (int k0 = 0; k0 < K; k0 += BK) {
    #pragma unroll
    for (int r = 0; r < 2; ++r) {
      const int li = t + r * 256;
      const int i = li >> 2;
      const int kc = (li & 3) << 2;
      float4 v = F4(A + (size_t)(row0 + i) * K + k0 + kc);
      As[kc + 0][i] = v.x; As[kc + 1][i] = v.y; As[kc + 2][i] = v.z; As[kc + 3][i] = v.w;
    }
    #pragma unroll
    for (int r = 0; r < 2; ++r) {
      const int li = t + r * 256;
      const int jj = li >> 2;
      const int kc = (li & 3) << 2;
      const int col = col0 + jj;
      const float* W = (col < H3_) ? Wf : Wb;
      const int wrow = (col < H3_) ? col : col - H3_;
      float4 v = F4(W + (size_t)wrow * K + k0 + kc);
      Bs[kc + 0][jj] = v.x; Bs[kc + 1][jj] = v.y; Bs[kc + 2][jj] = v.z; Bs[kc + 3][jj] = v.w;
    }
    __syncthreads();
    #pragma unroll
    for (int kk = 0; kk < BK; ++kk) {
      float a[TM], b[TN];
      const float4* a4 = (const float4*)&As[kk][ty * TM];
      const float4* b4 = (const float4*)&Bs[kk][tx * TN];
      float4 av0 = a4[0], av1 = a4[1], bv0 = b4[0], bv1 = b4[1];
      a[0]=av0.x; a[1]=av0.y; a[2]=av0.z; a[3]=av0.w; a[4]=av1.x; a[5]=av1.y; a[6]=av1.z; a[7]=av1.w;
      b[0]=bv0.x; b[1]=bv0.y; b[2]=bv0.z; b[3]=bv0.w; b[4]=bv1.x; b[5]=bv1.y; b[6]=bv1.z; b[7]=bv1.w;
      #pragma unroll
      for (int i = 0; i < TM; ++i)
        #pragma unroll
        for (int jq = 0; jq < TN; ++jq) acc[i][jq] = fmaf(a[i], b[jq], acc[i][jq]);
    }
    __syncthreads();
  }
  #pragma unroll
  for (int i = 0; i < TM; ++i) {
    const int row = row0 + ty * TM + i;
    #pragma unroll
    for (int jq = 0; jq < TN; ++jq) {
      const int col = col0 + tx * TN + jq;
      const int dir = (col >= H3_);
      const int jj = col - dir * H3_;
      const float bias = dir ? bb[jj] : bf[jj];
      xp[((size_t)dir * NL_ + row) * H3_ + jj] = acc[i][jq] + bias;
    }
  }
}

// ---------------- K5: GRU scan. One block per (dir, batch). 576 threads. ---
// f16-packed Whh row (96 u32) register-resident; each lane reads 1/4 of h
// from LDS (6 x b128), quarters circulated via DPP quad_perm broadcast.
__global__ __launch_bounds__(H3_, 1)
void gru_scan_kernel(const float* __restrict__ xp,            // [2][NL][576]
                     const unsigned int* __restrict__ Wpf,    // [24][576][4] f16-pairs
                     const unsigned int* __restrict__ Wpb,
                     const float* __restrict__ bhf,
                     const float* __restrict__ bhb,
                     float* __restrict__ hcat) {              // [NL][384]
  const int dir = blockIdx.x >> 4;
  const int n   = blockIdx.x & 15;
  const float* __restrict__ xpd = xp + ((size_t)dir * NL_ + (size_t)n * L_) * H3_;
  const unsigned int* __restrict__ Wp = dir ? Wpb : Wpf;
  const float* __restrict__ bh  = dir ? bhb : bhf;
  float* __restrict__ outd = hcat + (size_t)n * L_ * IN1_ + dir * H_;

  const int j = threadIdx.x;   // 0..575
  const int q = j & 3;         // quad lane

  __shared__ __align__(16) unsigned int h16[128];  // 96 used (192 f16), padded
  __shared__ float gh_lds[H3_];
  __shared__ float xn_lds[H_];

  // full f16-packed row j of Whh in registers: 24 x uint4 = 96 u32
  uint4 w[24];
  #pragma unroll
  for (int kc = 0; kc < 24; ++kc)
    w[kc] = ((const uint4*)Wp)[kc * H3_ + j];

  const float bj = bh[j];
  if (j < 128) h16[j] = 0u;
  float hprev = 0.f;                       // valid for j < H_
  __syncthreads();

  const uint4* __restrict__ h4 = (const uint4*)h16;   // 24 uint4
  const int ts = dir ? -1 : 1;
  int t = dir ? (L_ - 1) : 0;
  float xv = xpd[(size_t)t * H3_ + j];     // prefetched current step

  for (int tt = 0; tt < L_; ++tt) {
    float xvn = 0.f;
    if (tt + 1 < L_) xvn = xpd[(size_t)(t + ts) * H3_ + j];

    // self-read: this lane's quarter of h = u32s [24q .. 24q+23] (6 x b128)
    uint4 r0 = h4[q * 6 + 0], r1 = h4[q * 6 + 1], r2 = h4[q * 6 + 2];
    uint4 r3 = h4[q * 6 + 3], r4 = h4[q * 6 + 4], r5 = h4[q * 6 + 5];

    float a0 = bj, a1 = 0.f, a2 = 0.f, a3 = 0.f;
    // round R: broadcast quad-lane R's quarter (u32s 24R+4m+c), weights w[6R+m].c
    #define RND(R, A)                                                         \
      {                                                                       \
        uint4 rr[6] = {r0, r1, r2, r3, r4, r5};                               \
        _Pragma("unroll")                                                     \
        for (int m = 0; m < 6; ++m) {                                         \
          A = dot2acc(w[6 * R + m].x, qbcast<R>(rr[m].x), A);                 \
          A = dot2acc(w[6 * R + m].y, qbcast<R>(rr[m].y), A);                 \
          A = dot2acc(w[6 * R + m].z, qbcast<R>(rr[m].z), A);                 \
          A = dot2acc(w[6 * R + m].w, qbcast<R>(rr[m].w), A);                 \
        }                                                                     \
      }
    RND(0, a0) RND(1, a1) RND(2, a2) RND(3, a3)
    #undef RND
    float acc = (a0 + a1) + (a2 + a3);

    if (j < 2 * H_) acc += xv;
    gh_lds[j] = acc;
    if (j >= 2 * H_) xn_lds[j - 2 * H_] = xv;
    __syncthreads();

    if (j < H_) {
      const float r  = 1.f / (1.f + __expf(-gh_lds[j]));
      const float z  = 1.f / (1.f + __expf(-gh_lds[H_ + j]));
      const float nn = tanhf(xn_lds[j] + r * gh_lds[2 * H_ + j]);
      const float hnew = (1.f - z) * nn + z * hprev;
      hprev = hnew;
      H16U cv; cv.f = (_Float16)hnew;
      ((unsigned short*)h16)[j] = cv.s;    // ds_write_b16
      outd[(size_t)t * IN1_ + j] = hnew;
    }
    __syncthreads();

    xv = xvn;
    t += ts;
  }
}

// ---------------- K6: fused per-channel FFN + LayerNorm + ReLU + Linear ----
// Block: (d, 128 rows). 256 threads; thread owns W1 rows t and t+256 in regs.
__global__ __launch_bounds__(256)
void ffn_kernel(const float* __restrict__ hcat, const float* __restrict__ adm_out,
                const float* __restrict__ W1, const float* __restrict__ b1,
                const float* __restrict__ lng, const float* __restrict__ lnb,
                const float* __restrict__ W2, const float* __restrict__ b2,
                float* __restrict__ out) {
  constexpr int FROWS = 8;
  const int d = blockIdx.y;            // 12
  const int row_base = blockIdx.x * 128;
  const int t = threadIdx.x;
  const int lane = t & 63, w = t >> 6;

  __shared__ __align__(16) float featL[FROWS][48];
  __shared__ __align__(16) float hhL[FROWS][FFH_];
  __shared__ float gL[FFH_], bLn[FFH_], w2L[FFH_], b1L[FFH_];

  for (int i = t; i < FFH_; i += 256) {
    gL[i]  = lng[d * FFH_ + i];
    bLn[i] = lnb[d * FFH_ + i];
    w2L[i] = W2[d * FFH_ + i];
    b1L[i] = b1[d * FFH_ + i];
  }
  float w1a[48], w1b[48];
  {
    const float* ra = W1 + ((size_t)d * FFH_ + t) * 48;
    const float* rb = W1 + ((size_t)d * FFH_ + 256 + t) * 48;
    #pragma unroll
    for (int kc = 0; kc < 12; ++kc) {
      float4 va = F4(ra + kc * 4);
      w1a[4*kc+0]=va.x; w1a[4*kc+1]=va.y; w1a[4*kc+2]=va.z; w1a[4*kc+3]=va.w;
      float4 vb = F4(rb + kc * 4);
      w1b[4*kc+0]=vb.x; w1b[4*kc+1]=vb.y; w1b[4*kc+2]=vb.z; w1b[4*kc+3]=vb.w;
    }
  }
  const float b2v = b2[d];
  __syncthreads();

  for (int c0 = 0; c0 < 128; c0 += FROWS) {
    for (int idx = t; idx < FROWS * 48; idx += 256) {
      const int r = idx / 48, k = idx % 48;
      const int row = row_base + c0 + r;
      float v;
      if (k < 32) v = hcat[(size_t)row * IN1_ + d * 32 + k];
      else        v = adm_out[(row >> 10) * HID_ + (k - 32)];
      featL[r][k] = v;
    }
    __syncthreads();
    float acc_a[FROWS] = {}, acc_b[FROWS] = {};
    #pragma unroll
    for (int r = 0; r < FROWS; ++r) {
      const float4* f4 = (const float4*)featL[r];
      #pragma unroll
      for (int kc = 0; kc < 12; ++kc) {
        float4 f = f4[kc];
        acc_a[r] = fmaf(w1a[4*kc+0], f.x, acc_a[r]);
        acc_a[r] = fmaf(w1a[4*kc+1], f.y, acc_a[r]);
        acc_a[r] = fmaf(w1a[4*kc+2], f.z, acc_a[r]);
        acc_a[r] = fmaf(w1a[4*kc+3], f.w, acc_a[r]);
        acc_b[r] = fmaf(w1b[4*kc+0], f.x, acc_b[r]);
        acc_b[r] = fmaf(w1b[4*kc+1], f.y, acc_b[r]);
        acc_b[r] = fmaf(w1b[4*kc+2], f.z, acc_b[r]);
        acc_b[r] = fmaf(w1b[4*kc+3], f.w, acc_b[r]);
      }
    }
    #pragma unroll
    for (int r = 0; r < FROWS; ++r) {
      hhL[r][t]       = acc_a[r] + b1L[t];
      hhL[r][t + 256] = acc_b[r] + b1L[t + 256];
    }
    __syncthreads();
    // LayerNorm + ReLU + W2 reduce: wave w handles rows w and w+4
    #pragma unroll
    for (int rr = 0; rr < 2; ++rr) {
      const int r = w + rr * 4;
      const float4* h4 = (const float4*)hhL[r];
      float4 x0 = h4[lane * 2], x1 = h4[lane * 2 + 1];
      float s = x0.x + x0.y + x0.z + x0.w + x1.x + x1.y + x1.z + x1.w;
      float q = x0.x*x0.x + x0.y*x0.y + x0.z*x0.z + x0.w*x0.w
              + x1.x*x1.x + x1.y*x1.y + x1.z*x1.z + x1.w*x1.w;
      #pragma unroll
      for (int m = 1; m < 64; m <<= 1) { s += __shfl_xor(s, m); q += __shfl_xor(q, m); }
      const float mu   = s * (1.f / FFH_);
      const float var  = q * (1.f / FFH_) - mu * mu;
      const float rstd = rsqrtf(var + 1e-5f);
      const int col = lane * 8;
      const float xs[8] = {x0.x, x0.y, x0.z, x0.w, x1.x, x1.y, x1.z, x1.w};
      float o = 0.f;
      #pragma unroll
      for (int i = 0; i < 8; ++i) {
        float v = (xs[i] - mu) * rstd * gL[col + i] + bLn[col + i];
        v = fmaxf(v, 0.f);
        o = fmaf(v, w2L[col + i], o);
      }
      #pragma unroll
      for (int m = 1; m < 64; m <<= 1) o += __shfl_xor(o, m);
      if (lane == 0) {
        const int row = row_base + c0 + r;
        out[(size_t)row * D_ + d] = o + b2v;
      }
    }
    __syncthreads();
  }
}

// ---------------------------------------------------------------------------
extern "C" void kernel_launch(void* const* d_in, const int* in_sizes, int n_in,
                              void* d_out, int out_size, void* d_ws, size_t ws_size,
                              hipStream_t stream) {
  const float* series = (const float*)d_in[0];
  const float* adm    = (const float*)d_in[1];
  const int*   mask   = (const int*)  d_in[2];
  const float* sW     = (const float*)d_in[3];
  const float* membW  = (const float*)d_in[4];
  const float* aW1    = (const float*)d_in[5];
  const float* ab1    = (const float*)d_in[6];
  const float* aW2    = (const float*)d_in[7];
  const float* ab2    = (const float*)d_in[8];
  const float* Wih0f  = (const float*)d_in[9];
  const float* Whh0f  = (const float*)d_in[10];
  const float* bih0f  = (const float*)d_in[11];
  const float* bhh0f  = (const float*)d_in[12];
  const float* Wih0b  = (const float*)d_in[13];
  const float* Whh0b  = (const float*)d_in[14];
  const float* bih0b  = (const float*)d_in[15];
  const float* bhh0b  = (const float*)d_in[16];
  const float* Wih1f  = (const float*)d_in[17];
  const float* Whh1f  = (const float*)d_in[18];
  const float* bih1f  = (const float*)d_in[19];
  const float* bhh1f  = (const float*)d_in[20];
  const float* Wih1b  = (const float*)d_in[21];
  const float* Whh1b  = (const float*)d_in[22];
  const float* bih1b  = (const float*)d_in[23];
  const float* bhh1b  = (const float*)d_in[24];
  const float* ffnW1  = (const float*)d_in[25];
  const float* ffnb1  = (const float*)d_in[26];
  const float* lng    = (const float*)d_in[27];
  const float* lnb    = (const float*)d_in[28];
  const float* ffnW2  = (const float*)d_in[29];
  const float* ffnb2  = (const float*)d_in[30];
  float* outp = (float*)d_out;

  // workspace layout (floats)
  float* ws      = (float*)d_ws;
  float* adm_out = ws;                                   // 256
  float* emb     = adm_out + 256;                        // NL*96   = 1,572,864
  float* xp      = emb + (size_t)NL_ * IN0_;             // 2*NL*576= 18,874,368
  float* hcat    = xp + (size_t)2 * NL_ * H3_;           // NL*384  = 6,291,456
  unsigned int* wp0f = (unsigned int*)(hcat + (size_t)NL_ * IN1_);  // 55,296 u32 each
  unsigned int* wp0b = wp0f + (size_t)H3_ * 96;
  unsigned int* wp1f = wp0b + (size_t)H3_ * 96;
  unsigned int* wp1b = wp1f + (size_t)H3_ * 96;

  adm_mlp_kernel<<<1, 256, 0, stream>>>(adm, aW1, ab1, aW2, ab2, adm_out);
  embed_kernel<<<(NL_ * IN0_) / 256, 256, 0, stream>>>(series, mask, sW, membW, emb);
  whh_pack16_kernel<<<(H3_ * 96) / 256, 256, 0, stream>>>(Whh0f, wp0f);
  whh_pack16_kernel<<<(H3_ * 96) / 256, 256, 0, stream>>>(Whh0b, wp0b);
  whh_pack16_kernel<<<(H3_ * 96) / 256, 256, 0, stream>>>(Whh1f, wp1f);
  whh_pack16_kernel<<<(H3_ * 96) / 256, 256, 0, stream>>>(Whh1b, wp1b);

  // layer 0
  xp_gemm_kernel<<<dim3(NL_ / 128, (2 * H3_) / 128), 256, 0, stream>>>(
      emb, IN0_, Wih0f, Wih0b, bih0f, bih0b, xp);
  gru_scan_kernel<<<32, H3_, 0, stream>>>(xp, wp0f, wp0b, bhh0f, bhh0b, hcat);

  // layer 1 (xp buffer reused; hcat overwritten in place by scan output)
  xp_gemm_kernel<<<dim3(NL_ / 128, (2 * H3_) / 128), 256, 0, stream>>>(
      hcat, IN1_, Wih1f, Wih1b, bih1f, bih1b, xp);
  gru_scan_kernel<<<32, H3_, 0, stream>>>(xp, wp1f, wp1b, bhh1f, bhh1b, hcat);

  // fused FFN
  ffn_kernel<<<dim3(NL_ / 128, D_), 256, 0, stream>>>(
      hcat, adm_out, ffnW1, ffnb1, lng, lnb, ffnW2, ffnb2, outp);
}

// Round 8
// 3088.640 us; speedup vs baseline: 1.1226x; 1.1117x over previous
//
#include <hip/hip_runtime.h>
#include <math.h>

// ---------------------------------------------------------------------------
// MultiModalImputer forward.
// R8: within-run A/B on the scan.
//   layer 0: gru_scan_bl  — h broadcast via BATCHED readlane (chunks of 24
//            readlanes then 24 dot2s, sched_barrier-pinned). Removes the
//            per-pair SALU hazard that killed R5 and the 216 b128/step LDS
//            bottleneck of R4.
//   layer 1: gru_scan_r4  — exact R4 kernel (known 1057us) as control.
// Everything else identical to R4 (best total 2691us).
// ---------------------------------------------------------------------------

constexpr int N_   = 16;
constexpr int L_   = 1024;
constexpr int D_   = 12;
constexpr int E_   = 8;
constexpr int HID_ = 16;
constexpr int ADM_ = 64;
constexpr int H_   = 192;   // HID*D
constexpr int H3_  = 576;   // 3*H
constexpr int IN0_ = 96;    // D*E
constexpr int IN1_ = 384;   // 2*H
constexpr int NL_  = N_ * L_;  // 16384
constexpr int FFH_ = 512;

#define F4(p) (*(const float4*)(p))

typedef _Float16 half2v __attribute__((ext_vector_type(2)));
union U32H2 { unsigned int u; half2v h; };
union H16U { _Float16 f; unsigned short s; };

__device__ __forceinline__ float dot2acc(unsigned int wu, unsigned int hu, float acc) {
#if __has_builtin(__builtin_amdgcn_fdot2)
  U32H2 a, b; a.u = wu; b.u = hu;
  return __builtin_amdgcn_fdot2(a.h, b.h, acc, false);
#else
  U32H2 a, b; a.u = wu; b.u = hu;
  acc = fmaf((float)a.h.x, (float)b.h.x, acc);
  return fmaf((float)a.h.y, (float)b.h.y, acc);
#endif
}

// ---------------- K1: adm MLP: relu(adm@W1.T+b1)@W2.T+b2 -> [16,16] --------
__global__ void adm_mlp_kernel(const float* __restrict__ adm,
                               const float* __restrict__ W1, const float* __restrict__ b1,
                               const float* __restrict__ W2, const float* __restrict__ b2,
                               float* __restrict__ adm_out) {
  __shared__ float hid[N_][HID_];
  const int t = threadIdx.x;        // 256
  const int n = t >> 4, j = t & 15;
  float acc = b1[j];
  for (int k = 0; k < ADM_; ++k) acc = fmaf(adm[n * ADM_ + k], W1[j * ADM_ + k], acc);
  hid[n][j] = fmaxf(acc, 0.f);
  __syncthreads();
  float acc2 = b2[j];
  for (int k = 0; k < HID_; ++k) acc2 = fmaf(hid[n][k], W2[j * HID_ + k], acc2);
  adm_out[n * HID_ + j] = acc2;
}

// ---------------- K2: fused mask-embedding + per-channel Linear(1->8) ------
__global__ void embed_kernel(const float* __restrict__ series, const int* __restrict__ mask,
                             const float* __restrict__ sW, const float* __restrict__ membW,
                             float* __restrict__ emb) {
  const int i = blockIdx.x * blockDim.x + threadIdx.x;   // over NL*96
  if (i >= NL_ * IN0_) return;
  const int de = i % IN0_;
  const int nl = i / IN0_;
  const int d = de >> 3, e = de & 7;
  const float s = series[nl * D_ + d];
  const int   m = mask[nl * D_ + d];
  const int idx = m ? (d + 1) : 0;
  emb[i] = membW[idx * E_ + e] + s * sW[de];
}

// ------- K3: pack Whh [576][192] f32 -> [24][576][4] uint32 (f16 pairs) ----
// out[((kc*576 + j)*4 + c)] packs k = kc*8 + c*2 and k+1 of row j.
__global__ void whh_pack16_kernel(const float* __restrict__ Whh, unsigned int* __restrict__ Wp) {
  const int o = blockIdx.x * blockDim.x + threadIdx.x;   // 576*96 = 55296
  if (o >= H3_ * 96) return;
  const int c  = o & 3;
  const int j  = (o >> 2) % H3_;
  const int kc = (o >> 2) / H3_;
  const int k  = kc * 8 + c * 2;
  H16U lo, hi;
  lo.f = (_Float16)Whh[j * H_ + k];
  hi.f = (_Float16)Whh[j * H_ + k + 1];
  Wp[o] = (unsigned int)lo.s | ((unsigned int)hi.s << 16);
}

// ---------------- K4: xp GEMM: xp[dir][row][j] = A@W^T + bih ---------------
// A [NL][K] row-major, Wf/Wb [576][K] row-major. BM=BN=128, BK=16, 8x8/thread.
__global__ __launch_bounds__(256)
void xp_gemm_kernel(const float* __restrict__ A, const int K,
                    const float* __restrict__ Wf, const float* __restrict__ Wb,
                    const float* __restrict__ bf, const float* __restrict__ bb,
                    float* __restrict__ xp /* [2][NL][576] */) {
  constexpr int BM = 128, BN = 128, BK = 16, TM = 8, TN = 8;
  __shared__ float As[BK][BM + 4];
  __shared__ float Bs[BK][BN + 4];
  const int bm = blockIdx.x;   // 128
  const int bn = blockIdx.y;   // 9
  const int t = threadIdx.x;
  const int tx = t & 15, ty = t >> 4;
  const int row0 = bm * BM, col0 = bn * BN;
  float acc[TM][TN] = {};

  for (int k0 = 0; k0 < K; k0 += BK) {
    #pragma unroll
    for (int r = 0; r < 2; ++r) {
      const int li = t + r * 256;
      const int i = li >> 2;
      const int kc = (li & 3) << 2;
      float4 v = F4(A + (size_t)(row0 + i) * K + k0 + kc);
      As[kc + 0][i] = v.x; As[kc + 1][i] = v.y; As[kc + 2][i] = v.z; As[kc + 3][i] = v.w;
    }
    #pragma unroll
    for (int r = 0; r < 2; ++r) {
      const int li = t + r * 256;
      const int jj = li >> 2;
      const int kc = (li & 3) << 2;
      const int col = col0 + jj;
      const float* W = (col < H3_) ? Wf : Wb;
      const int wrow = (col < H3_) ? col : col - H3_;
      float4 v = F4(W + (size_t)wrow * K + k0 + kc);
      Bs[kc + 0][jj] = v.x; Bs[kc + 1][jj] = v.y; Bs[kc + 2][jj] = v.z; Bs[kc + 3][jj] = v.w;
    }
    __syncthreads();
    #pragma unroll
    for (int kk = 0; kk < BK; ++kk) {
      float a[TM], b[TN];
      const float4* a4 = (const float4*)&As[kk][ty * TM];
      const float4* b4 = (const float4*)&Bs[kk][tx * TN];
      float4 av0 = a4[0], av1 = a4[1], bv0 = b4[0], bv1 = b4[1];
      a[0]=av0.x; a[1]=av0.y; a[2]=av0.z; a[3]=av0.w; a[4]=av1.x; a[5]=av1.y; a[6]=av1.z; a[7]=av1.w;
      b[0]=bv0.x; b[1]=bv0.y; b[2]=bv0.z; b[3]=bv0.w; b[4]=bv1.x; b[5]=bv1.y; b[6]=bv1.z; b[7]=bv1.w;
      #pragma unroll
      for (int i = 0; i < TM; ++i)
        #pragma unroll
        for (int jq = 0; jq < TN; ++jq) acc[i][jq] = fmaf(a[i], b[jq], acc[i][jq]);
    }
    __syncthreads();
  }
  #pragma unroll
  for (int i = 0; i < TM; ++i) {
    const int row = row0 + ty * TM + i;
    #pragma unroll
    for (int jq = 0; jq < TN; ++jq) {
      const int col = col0 + tx * TN + jq;
      const int dir = (col >= H3_);
      const int jj = col - dir * H3_;
      const float bias = dir ? bb[jj] : bf[jj];
      xp[((size_t)dir * NL_ + row) * H3_ + jj] = acc[i][jq] + bias;
    }
  }
}

// ------- K5a: GRU scan, BATCHED-READLANE variant (layer 0 / A-side) --------
__global__ __launch_bounds__(H3_, 1)
void gru_scan_bl(const float* __restrict__ xp,            // [2][NL][576]
                 const unsigned int* __restrict__ Wpf,    // [24][576][4] f16-pairs
                 const unsigned int* __restrict__ Wpb,
                 const float* __restrict__ bhf,
                 const float* __restrict__ bhb,
                 float* __restrict__ hcat) {              // [NL][384]
  const int dir = blockIdx.x >> 4;
  const int n   = blockIdx.x & 15;
  const float* __restrict__ xpd = xp + ((size_t)dir * NL_ + (size_t)n * L_) * H3_;
  const unsigned int* __restrict__ Wp = dir ? Wpb : Wpf;
  const float* __restrict__ bh  = dir ? bhb : bhf;
  float* __restrict__ outd = hcat + (size_t)n * L_ * IN1_ + dir * H_;

  const int j = threadIdx.x;   // 0..575
  const int lane = j & 63;

  __shared__ __align__(16) unsigned int h16[128];  // 96 used (192 f16), padded
  __shared__ float gh_lds[H3_];
  __shared__ float xn_lds[H_];

  uint4 w[24];
  #pragma unroll
  for (int kc = 0; kc < 24; ++kc)
    w[kc] = ((const uint4*)Wp)[kc * H3_ + j];

  const float bj = bh[j];
  if (j < 128) h16[j] = 0u;
  float hprev = 0.f;                       // valid for j < H_
  __syncthreads();

  const int ts = dir ? -1 : 1;
  int t = dir ? (L_ - 1) : 0;
  float xv = xpd[(size_t)t * H3_ + j];     // prefetched current step

  for (int tt = 0; tt < L_; ++tt) {
    float xvn = 0.f;
    if (tt + 1 < L_) xvn = xpd[(size_t)(t + ts) * H3_ + j];

    // one ds_read_b64 per lane: lane l holds h-u32 pair (2l, 2l+1)
    uint2 hp = ((const uint2*)h16)[lane];

    float a0 = bj, a1 = 0.f, a2 = 0.f, a3 = 0.f;
    // 4 chunks: 24 readlanes (uniform->SGPR), fence, then 24 dot2s.
    #pragma unroll
    for (int c = 0; c < 4; ++c) {
      unsigned int hs[24];
      #pragma unroll
      for (int i = 0; i < 24; ++i) {
        const int q = 24 * c + i;                       // u32 index in h
        hs[i] = (unsigned int)__builtin_amdgcn_readlane(
                    (int)((q & 1) ? hp.y : hp.x), q >> 1);
      }
      __builtin_amdgcn_sched_barrier(0);                // keep readlanes batched
      #pragma unroll
      for (int m = 0; m < 6; ++m) {
        const int kc = 6 * c + m;
        a0 = dot2acc(w[kc].x, hs[4 * m + 0], a0);
        a1 = dot2acc(w[kc].y, hs[4 * m + 1], a1);
        a2 = dot2acc(w[kc].z, hs[4 * m + 2], a2);
        a3 = dot2acc(w[kc].w, hs[4 * m + 3], a3);
      }
      __builtin_amdgcn_sched_barrier(0);
    }
    float acc = (a0 + a1) + (a2 + a3);

    if (j < 2 * H_) acc += xv;
    gh_lds[j] = acc;
    if (j >= 2 * H_) xn_lds[j - 2 * H_] = xv;
    __syncthreads();

    if (j < H_) {
      const float r  = 1.f / (1.f + __expf(-gh_lds[j]));
      const float z  = 1.f / (1.f + __expf(-gh_lds[H_ + j]));
      const float nn = tanhf(xn_lds[j] + r * gh_lds[2 * H_ + j]);
      const float hnew = (1.f - z) * nn + z * hprev;
      hprev = hnew;
      H16U cv; cv.f = (_Float16)hnew;
      ((unsigned short*)h16)[j] = cv.s;    // ds_write_b16
      outd[(size_t)t * IN1_ + j] = hnew;
    }
    __syncthreads();

    xv = xvn;
    t += ts;
  }
}

// ------- K5b: GRU scan, exact-R4 control (layer 1 / B-side) ----------------
__global__ __launch_bounds__(H3_, 1)
void gru_scan_r4(const float* __restrict__ xp,            // [2][NL][576]
                 const unsigned int* __restrict__ Wpf,    // [24][576][4] f16-pairs
                 const unsigned int* __restrict__ Wpb,
                 const float* __restrict__ bhf,
                 const float* __restrict__ bhb,
                 float* __restrict__ hcat) {              // [NL][384]
  const int dir = blockIdx.x >> 4;
  const int n   = blockIdx.x & 15;
  const float* __restrict__ xpd = xp + ((size_t)dir * NL_ + (size_t)n * L_) * H3_;
  const unsigned int* __restrict__ Wp = dir ? Wpb : Wpf;
  const float* __restrict__ bh  = dir ? bhb : bhf;
  float* __restrict__ outd = hcat + (size_t)n * L_ * IN1_ + dir * H_;

  const int j = threadIdx.x;   // 0..575

  __shared__ __align__(16) unsigned int h16[128];  // 96 used (192 f16), padded
  __shared__ float gh_lds[H3_];
  __shared__ float xn_lds[H_];

  uint4 w[24];
  #pragma unroll
  for (int kc = 0; kc < 24; ++kc)
    w[kc] = ((const uint4*)Wp)[kc * H3_ + j];

  const float bj = bh[j];
  if (j < 128) h16[j] = 0u;
  float hprev = 0.f;                       // valid for j < H_
  __syncthreads();

  const uint4* __restrict__ h4 = (const uint4*)h16;
  const int ts = dir ? -1 : 1;
  int t = dir ? (L_ - 1) : 0;
  float xv = xpd[(size_t)t * H3_ + j];     // prefetched current step

  for (int tt = 0; tt < L_; ++tt) {
    float xvn = 0.f;
    if (tt + 1 < L_) xvn = xpd[(size_t)(t + ts) * H3_ + j];

    float a0 = bj, a1 = 0.f, a2 = 0.f, a3 = 0.f;
    #pragma unroll
    for (int kc = 0; kc < 24; ++kc) {
      uint4 hv = h4[kc];                   // broadcast: same addr across wave
      a0 = dot2acc(w[kc].x, hv.x, a0);
      a1 = dot2acc(w[kc].y, hv.y, a1);
      a2 = dot2acc(w[kc].z, hv.z, a2);
      a3 = dot2acc(w[kc].w, hv.w, a3);
    }
    float acc = (a0 + a1) + (a2 + a3);

    if (j < 2 * H_) acc += xv;
    gh_lds[j] = acc;
    if (j >= 2 * H_) xn_lds[j - 2 * H_] = xv;
    __syncthreads();

    if (j < H_) {
      const float r  = 1.f / (1.f + __expf(-gh_lds[j]));
      const float z  = 1.f / (1.f + __expf(-gh_lds[H_ + j]));
      const float nn = tanhf(xn_lds[j] + r * gh_lds[2 * H_ + j]);
      const float hnew = (1.f - z) * nn + z * hprev;
      hprev = hnew;
      H16U cv; cv.f = (_Float16)hnew;
      ((unsigned short*)h16)[j] = cv.s;    // ds_write_b16
      outd[(size_t)t * IN1_ + j] = hnew;
    }
    __syncthreads();

    xv = xvn;
    t += ts;
  }
}

// ---------------- K6: fused per-channel FFN + LayerNorm + ReLU + Linear ----
// Block: (d, 128 rows). 256 threads; thread owns W1 rows t and t+256 in regs.
__global__ __launch_bounds__(256)
void ffn_kernel(const float* __restrict__ hcat, const float* __restrict__ adm_out,
                const float* __restrict__ W1, const float* __restrict__ b1,
                const float* __restrict__ lng, const float* __restrict__ lnb,
                const float* __restrict__ W2, const float* __restrict__ b2,
                float* __restrict__ out) {
  constexpr int FROWS = 8;
  const int d = blockIdx.y;            // 12
  const int row_base = blockIdx.x * 128;
  const int t = threadIdx.x;
  const int lane = t & 63, w = t >> 6;

  __shared__ __align__(16) float featL[FROWS][48];
  __shared__ __align__(16) float hhL[FROWS][FFH_];
  __shared__ float gL[FFH_], bLn[FFH_], w2L[FFH_], b1L[FFH_];

  for (int i = t; i < FFH_; i += 256) {
    gL[i]  = lng[d * FFH_ + i];
    bLn[i] = lnb[d * FFH_ + i];
    w2L[i] = W2[d * FFH_ + i];
    b1L[i] = b1[d * FFH_ + i];
  }
  float w1a[48], w1b[48];
  {
    const float* ra = W1 + ((size_t)d * FFH_ + t) * 48;
    const float* rb = W1 + ((size_t)d * FFH_ + 256 + t) * 48;
    #pragma unroll
    for (int kc = 0; kc < 12; ++kc) {
      float4 va = F4(ra + kc * 4);
      w1a[4*kc+0]=va.x; w1a[4*kc+1]=va.y; w1a[4*kc+2]=va.z; w1a[4*kc+3]=va.w;
      float4 vb = F4(rb + kc * 4);
      w1b[4*kc+0]=vb.x; w1b[4*kc+1]=vb.y; w1b[4*kc+2]=vb.z; w1b[4*kc+3]=vb.w;
    }
  }
  const float b2v = b2[d];
  __syncthreads();

  for (int c0 = 0; c0 < 128; c0 += FROWS) {
    for (int idx = t; idx < FROWS * 48; idx += 256) {
      const int r = idx / 48, k = idx % 48;
      const int row = row_base + c0 + r;
      float v;
      if (k < 32) v = hcat[(size_t)row * IN1_ + d * 32 + k];
      else        v = adm_out[(row >> 10) * HID_ + (k - 32)];
      featL[r][k] = v;
    }
    __syncthreads();
    float acc_a[FROWS] = {}, acc_b[FROWS] = {};
    #pragma unroll
    for (int r = 0; r < FROWS; ++r) {
      const float4* f4 = (const float4*)featL[r];
      #pragma unroll
      for (int kc = 0; kc < 12; ++kc) {
        float4 f = f4[kc];
        acc_a[r] = fmaf(w1a[4*kc+0], f.x, acc_a[r]);
        acc_a[r] = fmaf(w1a[4*kc+1], f.y, acc_a[r]);
        acc_a[r] = fmaf(w1a[4*kc+2], f.z, acc_a[r]);
        acc_a[r] = fmaf(w1a[4*kc+3], f.w, acc_a[r]);
        acc_b[r] = fmaf(w1b[4*kc+0], f.x, acc_b[r]);
        acc_b[r] = fmaf(w1b[4*kc+1], f.y, acc_b[r]);
        acc_b[r] = fmaf(w1b[4*kc+2], f.z, acc_b[r]);
        acc_b[r] = fmaf(w1b[4*kc+3], f.w, acc_b[r]);
      }
    }
    #pragma unroll
    for (int r = 0; r < FROWS; ++r) {
      hhL[r][t]       = acc_a[r] + b1L[t];
      hhL[r][t + 256] = acc_b[r] + b1L[t + 256];
    }
    __syncthreads();
    // LayerNorm + ReLU + W2 reduce: wave w handles rows w and w+4
    #pragma unroll
    for (int rr = 0; rr < 2; ++rr) {
      const int r = w + rr * 4;
      const float4* h4 = (const float4*)hhL[r];
      float4 x0 = h4[lane * 2], x1 = h4[lane * 2 + 1];
      float s = x0.x + x0.y + x0.z + x0.w + x1.x + x1.y + x1.z + x1.w;
      float q = x0.x*x0.x + x0.y*x0.y + x0.z*x0.z + x0.w*x0.w
              + x1.x*x1.x + x1.y*x1.y + x1.z*x1.z + x1.w*x1.w;
      #pragma unroll
      for (int m = 1; m < 64; m <<= 1) { s += __shfl_xor(s, m); q += __shfl_xor(q, m); }
      const float mu   = s * (1.f / FFH_);
      const float var  = q * (1.f / FFH_) - mu * mu;
      const float rstd = rsqrtf(var + 1e-5f);
      const int col = lane * 8;
      const float xs[8] = {x0.x, x0.y, x0.z, x0.w, x1.x, x1.y, x1.z, x1.w};
      float o = 0.f;
      #pragma unroll
      for (int i = 0; i < 8; ++i) {
        float v = (xs[i] - mu) * rstd * gL[col + i] + bLn[col + i];
        v = fmaxf(v, 0.f);
        o = fmaf(v, w2L[col + i], o);
      }
      #pragma unroll
      for (int m = 1; m < 64; m <<= 1) o += __shfl_xor(o, m);
      if (lane == 0) {
        const int row = row_base + c0 + r;
        out[(size_t)row * D_ + d] = o + b2v;
      }
    }
    __syncthreads();
  }
}

// ---------------------------------------------------------------------------
extern "C" void kernel_launch(void* const* d_in, const int* in_sizes, int n_in,
                              void* d_out, int out_size, void* d_ws, size_t ws_size,
                              hipStream_t stream) {
  const float* series = (const float*)d_in[0];
  const float* adm    = (const float*)d_in[1];
  const int*   mask   = (const int*)  d_in[2];
  const float* sW     = (const float*)d_in[3];
  const float* membW  = (const float*)d_in[4];
  const float* aW1    = (const float*)d_in[5];
  const float* ab1    = (const float*)d_in[6];
  const float* aW2    = (const float*)d_in[7];
  const float* ab2    = (const float*)d_in[8];
  const float* Wih0f  = (const float*)d_in[9];
  const float* Whh0f  = (const float*)d_in[10];
  const float* bih0f  = (const float*)d_in[11];
  const float* bhh0f  = (const float*)d_in[12];
  const float* Wih0b  = (const float*)d_in[13];
  const float* Whh0b  = (const float*)d_in[14];
  const float* bih0b  = (const float*)d_in[15];
  const float* bhh0b  = (const float*)d_in[16];
  const float* Wih1f  = (const float*)d_in[17];
  const float* Whh1f  = (const float*)d_in[18];
  const float* bih1f  = (const float*)d_in[19];
  const float* bhh1f  = (const float*)d_in[20];
  const float* Wih1b  = (const float*)d_in[21];
  const float* Whh1b  = (const float*)d_in[22];
  const float* bih1b  = (const float*)d_in[23];
  const float* bhh1b  = (const float*)d_in[24];
  const float* ffnW1  = (const float*)d_in[25];
  const float* ffnb1  = (const float*)d_in[26];
  const float* lng    = (const float*)d_in[27];
  const float* lnb    = (const float*)d_in[28];
  const float* ffnW2  = (const float*)d_in[29];
  const float* ffnb2  = (const float*)d_in[30];
  float* outp = (float*)d_out;

  // workspace layout (floats)
  float* ws      = (float*)d_ws;
  float* adm_out = ws;                                   // 256
  float* emb     = adm_out + 256;                        // NL*96   = 1,572,864
  float* xp      = emb + (size_t)NL_ * IN0_;             // 2*NL*576= 18,874,368
  float* hcat    = xp + (size_t)2 * NL_ * H3_;           // NL*384  = 6,291,456
  unsigned int* wp0f = (unsigned int*)(hcat + (size_t)NL_ * IN1_);  // 55,296 u32 each
  unsigned int* wp0b = wp0f + (size_t)H3_ * 96;
  unsigned int* wp1f = wp0b + (size_t)H3_ * 96;
  unsigned int* wp1b = wp1f + (size_t)H3_ * 96;

  adm_mlp_kernel<<<1, 256, 0, stream>>>(adm, aW1, ab1, aW2, ab2, adm_out);
  embed_kernel<<<(NL_ * IN0_) / 256, 256, 0, stream>>>(series, mask, sW, membW, emb);
  whh_pack16_kernel<<<(H3_ * 96) / 256, 256, 0, stream>>>(Whh0f, wp0f);
  whh_pack16_kernel<<<(H3_ * 96) / 256, 256, 0, stream>>>(Whh0b, wp0b);
  whh_pack16_kernel<<<(H3_ * 96) / 256, 256, 0, stream>>>(Whh1f, wp1f);
  whh_pack16_kernel<<<(H3_ * 96) / 256, 256, 0, stream>>>(Whh1b, wp1b);

  // layer 0 — batched-readlane variant (A-side of the A/B)
  xp_gemm_kernel<<<dim3(NL_ / 128, (2 * H3_) / 128), 256, 0, stream>>>(
      emb, IN0_, Wih0f, Wih0b, bih0f, bih0b, xp);
  gru_scan_bl<<<32, H3_, 0, stream>>>(xp, wp0f, wp0b, bhh0f, bhh0b, hcat);

  // layer 1 — exact-R4 control (B-side)
  xp_gemm_kernel<<<dim3(NL_ / 128, (2 * H3_) / 128), 256, 0, stream>>>(
      hcat, IN1_, Wih1f, Wih1b, bih1f, bih1b, xp);
  gru_scan_r4<<<32, H3_, 0, stream>>>(xp, wp1f, wp1b, bhh1f, bhh1b, hcat);

  // fused FFN
  ffn_kernel<<<dim3(NL_ / 128, D_), 256, 0, stream>>>(
      hcat, adm_out, ffnW1, ffnb1, lng, lnb, ffnW2, ffnb2, outp);
}

// Round 10
// 2733.629 us; speedup vs baseline: 1.2684x; 1.1299x over previous
//
#include <hip/hip_runtime.h>
#include <math.h>

// ---------------------------------------------------------------------------
// MultiModalImputer forward.
// R9: MFMA GRU scan (A/B-guarded).
//   layer 0: gru_scan_mf — 8 blocks (4/dir x 4 batches), 512 thr. Per step
//            D[576,4] = Whh@h via mfma_f32_16x16x32_f16; W stationary in
//            VGPRs as A-fragments; h[16][200] f16 in LDS; D->LDS roundtrip
//            for gate gather; h_prev in owning thread's register.
//   layer 1: gru_scan_r4 — exact R4 control (1057us).
// R4's dot2 scan is at its LDS floor (216 b128/step = 2592cy ~= measured
// 2477cy); the MFMA pipe does the h-broadcast for free.
// ---------------------------------------------------------------------------

constexpr int N_   = 16;
constexpr int L_   = 1024;
constexpr int D_   = 12;
constexpr int E_   = 8;
constexpr int HID_ = 16;
constexpr int ADM_ = 64;
constexpr int H_   = 192;   // HID*D
constexpr int H3_  = 576;   // 3*H
constexpr int IN0_ = 96;    // D*E
constexpr int IN1_ = 384;   // 2*H
constexpr int NL_  = N_ * L_;  // 16384
constexpr int FFH_ = 512;

#define F4(p) (*(const float4*)(p))

typedef _Float16 half2v __attribute__((ext_vector_type(2)));
typedef _Float16 f16x8  __attribute__((ext_vector_type(8)));
typedef float    f32x4  __attribute__((ext_vector_type(4)));
union U32H2 { unsigned int u; half2v h; };
union H16U  { _Float16 f; unsigned short s; };
union FU    { uint4 u; f16x8 h; };

__device__ __forceinline__ float dot2acc(unsigned int wu, unsigned int hu, float acc) {
#if __has_builtin(__builtin_amdgcn_fdot2)
  U32H2 a, b; a.u = wu; b.u = hu;
  return __builtin_amdgcn_fdot2(a.h, b.h, acc, false);
#else
  U32H2 a, b; a.u = wu; b.u = hu;
  acc = fmaf((float)a.h.x, (float)b.h.x, acc);
  return fmaf((float)a.h.y, (float)b.h.y, acc);
#endif
}

// ---------------- K1: adm MLP: relu(adm@W1.T+b1)@W2.T+b2 -> [16,16] --------
__global__ void adm_mlp_kernel(const float* __restrict__ adm,
                               const float* __restrict__ W1, const float* __restrict__ b1,
                               const float* __restrict__ W2, const float* __restrict__ b2,
                               float* __restrict__ adm_out) {
  __shared__ float hid[N_][HID_];
  const int t = threadIdx.x;        // 256
  const int n = t >> 4, j = t & 15;
  float acc = b1[j];
  for (int k = 0; k < ADM_; ++k) acc = fmaf(adm[n * ADM_ + k], W1[j * ADM_ + k], acc);
  hid[n][j] = fmaxf(acc, 0.f);
  __syncthreads();
  float acc2 = b2[j];
  for (int k = 0; k < HID_; ++k) acc2 = fmaf(hid[n][k], W2[j * HID_ + k], acc2);
  adm_out[n * HID_ + j] = acc2;
}

// ---------------- K2: fused mask-embedding + per-channel Linear(1->8) ------
__global__ void embed_kernel(const float* __restrict__ series, const int* __restrict__ mask,
                             const float* __restrict__ sW, const float* __restrict__ membW,
                             float* __restrict__ emb) {
  const int i = blockIdx.x * blockDim.x + threadIdx.x;   // over NL*96
  if (i >= NL_ * IN0_) return;
  const int de = i % IN0_;
  const int nl = i / IN0_;
  const int d = de >> 3, e = de & 7;
  const float s = series[nl * D_ + d];
  const int   m = mask[nl * D_ + d];
  const int idx = m ? (d + 1) : 0;
  emb[i] = membW[idx * E_ + e] + s * sW[de];
}

// ------- K3a: pack Whh [576][192] f32 -> [24][576][4] uint32 (f16 pairs) ---
// (layer-1 control scan layout)
__global__ void whh_pack16_kernel(const float* __restrict__ Whh, unsigned int* __restrict__ Wp) {
  const int o = blockIdx.x * blockDim.x + threadIdx.x;   // 576*96 = 55296
  if (o >= H3_ * 96) return;
  const int c  = o & 3;
  const int j  = (o >> 2) % H3_;
  const int kc = (o >> 2) / H3_;
  const int k  = kc * 8 + c * 2;
  H16U lo, hi;
  lo.f = (_Float16)Whh[j * H_ + k];
  hi.f = (_Float16)Whh[j * H_ + k + 1];
  Wp[o] = (unsigned int)lo.s | ((unsigned int)hi.s << 16);
}

// ------- K3b: pack Whh -> MFMA A-fragment layout (f16) ---------------------
// frag (jt 0..35, kc 0..5): lane l, elem e holds W[jt*16+(l&15)][kc*32+(l>>4)*8+e]
// linear u32 index o: e2=o&3 (f16 pair), lane=(o>>2)&63, tile=o>>8 (jt*6+kc)
__global__ void wmf_pack16_kernel(const float* __restrict__ Whh, unsigned int* __restrict__ Wp) {
  const int o = blockIdx.x * blockDim.x + threadIdx.x;   // 216*64*4 = 55296
  if (o >= 216 * 256) return;
  const int e2   = o & 3;
  const int lane = (o >> 2) & 63;
  const int tile = o >> 8;
  const int jt = tile / 6, kc = tile % 6;
  const int row = jt * 16 + (lane & 15);
  const int k   = kc * 32 + (lane >> 4) * 8 + e2 * 2;
  H16U lo, hi;
  lo.f = (_Float16)Whh[row * H_ + k];
  hi.f = (_Float16)Whh[row * H_ + k + 1];
  Wp[o] = (unsigned int)lo.s | ((unsigned int)hi.s << 16);
}

// ---------------- K4: xp GEMM: xp[dir][row][j] = A@W^T + bih ---------------
__global__ __launch_bounds__(256)
void xp_gemm_kernel(const float* __restrict__ A, const int K,
                    const float* __restrict__ Wf, const float* __restrict__ Wb,
                    const float* __restrict__ bf, const float* __restrict__ bb,
                    float* __restrict__ xp /* [2][NL][576] */) {
  constexpr int BM = 128, BN = 128, BK = 16, TM = 8, TN = 8;
  __shared__ float As[BK][BM + 4];
  __shared__ float Bs[BK][BN + 4];
  const int bm = blockIdx.x;   // 128
  const int bn = blockIdx.y;   // 9
  const int t = threadIdx.x;
  const int tx = t & 15, ty = t >> 4;
  const int row0 = bm * BM, col0 = bn * BN;
  float acc[TM][TN] = {};

  for (int k0 = 0; k0 < K; k0 += BK) {
    #pragma unroll
    for (int r = 0; r < 2; ++r) {
      const int li = t + r * 256;
      const int i = li >> 2;
      const int kc = (li & 3) << 2;
      float4 v = F4(A + (size_t)(row0 + i) * K + k0 + kc);
      As[kc + 0][i] = v.x; As[kc + 1][i] = v.y; As[kc + 2][i] = v.z; As[kc + 3][i] = v.w;
    }
    #pragma unroll
    for (int r = 0; r < 2; ++r) {
      const int li = t + r * 256;
      const int jj = li >> 2;
      const int kc = (li & 3) << 2;
      const int col = col0 + jj;
      const float* W = (col < H3_) ? Wf : Wb;
      const int wrow = (col < H3_) ? col : col - H3_;
      float4 v = F4(W + (size_t)wrow * K + k0 + kc);
      Bs[kc + 0][jj] = v.x; Bs[kc + 1][jj] = v.y; Bs[kc + 2][jj] = v.z; Bs[kc + 3][jj] = v.w;
    }
    __syncthreads();
    #pragma unroll
    for (int kk = 0; kk < BK; ++kk) {
      float a[TM], b[TN];
      const float4* a4 = (const float4*)&As[kk][ty * TM];
      const float4* b4 = (const float4*)&Bs[kk][tx * TN];
      float4 av0 = a4[0], av1 = a4[1], bv0 = b4[0], bv1 = b4[1];
      a[0]=av0.x; a[1]=av0.y; a[2]=av0.z; a[3]=av0.w; a[4]=av1.x; a[5]=av1.y; a[6]=av1.z; a[7]=av1.w;
      b[0]=bv0.x; b[1]=bv0.y; b[2]=bv0.z; b[3]=bv0.w; b[4]=bv1.x; b[5]=bv1.y; b[6]=bv1.z; b[7]=bv1.w;
      #pragma unroll
      for (int i = 0; i < TM; ++i)
        #pragma unroll
        for (int jq = 0; jq < TN; ++jq) acc[i][jq] = fmaf(a[i], b[jq], acc[i][jq]);
    }
    __syncthreads();
  }
  #pragma unroll
  for (int i = 0; i < TM; ++i) {
    const int row = row0 + ty * TM + i;
    #pragma unroll
    for (int jq = 0; jq < TN; ++jq) {
      const int col = col0 + tx * TN + jq;
      const int dir = (col >= H3_);
      const int jj = col - dir * H3_;
      const float bias = dir ? bb[jj] : bf[jj];
      xp[((size_t)dir * NL_ + row) * H3_ + jj] = acc[i][jq] + bias;
    }
  }
}

// ------- K5a: MFMA GRU scan (layer 0). 8 blocks = 2 dir x 4 batch-groups ---
__global__ __launch_bounds__(512, 2)
void gru_scan_mf(const float* __restrict__ xp,            // [2][NL][576] f32
                 const unsigned int* __restrict__ WmfF,   // frag-packed f16
                 const unsigned int* __restrict__ WmfB,
                 const float* __restrict__ bhf,
                 const float* __restrict__ bhb,
                 float* __restrict__ hcat) {              // [NL][384]
  const int dir = blockIdx.x >> 2;
  const int n0  = (blockIdx.x & 3) * 4;
  const int tid = threadIdx.x, lane = tid & 63, wv = tid >> 6;
  const uint4* __restrict__ Wm = (const uint4*)(dir ? WmfB : WmfF);
  const float* __restrict__ bh = dir ? bhb : bhf;

  __shared__ __align__(16) _Float16 hT[16][200];   // h[b][k], rows>=4 stay 0
  __shared__ __align__(16) float    DL[4][592];    // D[b][j]

  // stationary W fragments: wave wv owns tiles jt = wv + 8*s
  const int nt = (wv < 4) ? 5 : 4;
  FU wf[5][6];
  #pragma unroll
  for (int s = 0; s < 5; ++s) {
    if (s < nt) {
      const int jt = wv + 8 * s;
      #pragma unroll
      for (int kc = 0; kc < 6; ++kc)
        wf[s][kc].u = Wm[(jt * 6 + kc) * 64 + lane];
    }
  }

  for (int i = tid; i < 1600; i += 512) ((unsigned int*)hT)[i] = 0u;

  // gate tasks: task = (b = task&3, i = task>>2); thread owns tid and tid+512
  const int  b0 = tid & 3, i0 = tid >> 2;           // i0 in 0..127
  const bool has1 = (tid < 256);
  const int  b1 = (tid + 512) & 3;
  const int  i1 = has1 ? ((tid + 512) >> 2) : 0;    // 128..191
  const float bh0r = bh[i0], bh0z = bh[i0 + 192], bh0n = bh[i0 + 384];
  const float bh1r = has1 ? bh[i1] : 0.f;
  const float bh1z = has1 ? bh[i1 + 192] : 0.f;
  const float bh1n = has1 ? bh[i1 + 384] : 0.f;
  const float* __restrict__ xp0 = xp + ((size_t)dir * NL_ + (size_t)(n0 + b0) * L_) * H3_;
  const float* __restrict__ xp1 = xp + ((size_t)dir * NL_ + (size_t)(n0 + b1) * L_) * H3_;
  float* __restrict__ hc0 = hcat + (size_t)(n0 + b0) * L_ * IN1_ + dir * H_ + i0;
  float* __restrict__ hc1 = hcat + (size_t)(n0 + b1) * L_ * IN1_ + dir * H_ + i1;

  const int ts = dir ? -1 : 1;
  int t = dir ? (L_ - 1) : 0;
  float x0r = xp0[(size_t)t * H3_ + i0];
  float x0z = xp0[(size_t)t * H3_ + i0 + 192];
  float x0n = xp0[(size_t)t * H3_ + i0 + 384];
  float x1r = 0.f, x1z = 0.f, x1n = 0.f;
  if (has1) {
    x1r = xp1[(size_t)t * H3_ + i1];
    x1z = xp1[(size_t)t * H3_ + i1 + 192];
    x1n = xp1[(size_t)t * H3_ + i1 + 384];
  }
  float h0p = 0.f, h1p = 0.f;
  __syncthreads();

  for (int tt = 0; tt < L_; ++tt) {
    // h B-fragments (same for all waves): lane&15 = batch col, lane>>4 = k-grp
    FU hb[6];
    #pragma unroll
    for (int kc = 0; kc < 6; ++kc)
      hb[kc].h = *(const f16x8*)&hT[lane & 15][kc * 32 + (lane >> 4) * 8];

    f32x4 acc[5];
    #pragma unroll
    for (int s = 0; s < 5; ++s) acc[s] = (f32x4){0.f, 0.f, 0.f, 0.f};
    #pragma unroll
    for (int kc = 0; kc < 6; ++kc) {
      #pragma unroll
      for (int s = 0; s < 5; ++s)
        if (s < nt)
          acc[s] = __builtin_amdgcn_mfma_f32_16x16x32_f16(wf[s][kc].h, hb[kc].h, acc[s], 0, 0, 0);
    }

    // prefetch next step's xp while MFMAs drain
    float y0r = 0.f, y0z = 0.f, y0n = 0.f, y1r = 0.f, y1z = 0.f, y1n = 0.f;
    if (tt + 1 < L_) {
      const size_t o = (size_t)(t + ts) * H3_;
      y0r = xp0[o + i0]; y0z = xp0[o + i0 + 192]; y0n = xp0[o + i0 + 384];
      if (has1) { y1r = xp1[o + i1]; y1z = xp1[o + i1 + 192]; y1n = xp1[o + i1 + 384]; }
    }

    // D -> LDS: lane l, reg q holds D[j = jt*16+4*(l>>4)+q][batch = l&15]
    if ((lane & 15) < 4) {
      #pragma unroll
      for (int s = 0; s < 5; ++s)
        if (s < nt) {
          const int jt = wv + 8 * s;
          *(f32x4*)&DL[lane & 15][jt * 16 + (lane >> 4) * 4] = acc[s];
        }
    }
    __syncthreads();

    // gates: gh = D + bhh; r=sig(x+ghr), z=sig(x+ghz), n=tanh(xn + r*ghn)
    {
      const float r  = 1.f / (1.f + __expf(-(x0r + DL[b0][i0]       + bh0r)));
      const float z  = 1.f / (1.f + __expf(-(x0z + DL[b0][i0 + 192] + bh0z)));
      const float nn = tanhf(x0n + r * (DL[b0][i0 + 384] + bh0n));
      const float hn = (1.f - z) * nn + z * h0p;
      h0p = hn;
      H16U cv; cv.f = (_Float16)hn;
      ((unsigned short*)&hT[b0][0])[i0] = cv.s;
      hc0[(size_t)t * IN1_] = hn;
    }
    if (has1) {
      const float r  = 1.f / (1.f + __expf(-(x1r + DL[b1][i1]       + bh1r)));
      const float z  = 1.f / (1.f + __expf(-(x1z + DL[b1][i1 + 192] + bh1z)));
      const float nn = tanhf(x1n + r * (DL[b1][i1 + 384] + bh1n));
      const float hn = (1.f - z) * nn + z * h1p;
      h1p = hn;
      H16U cv; cv.f = (_Float16)hn;
      ((unsigned short*)&hT[b1][0])[i1] = cv.s;
      hc1[(size_t)t * IN1_] = hn;
    }
    __syncthreads();

    x0r = y0r; x0z = y0z; x0n = y0n; x1r = y1r; x1z = y1z; x1n = y1n;
    t += ts;
  }
}

// ------- K5b: GRU scan, exact-R4 control (layer 1) -------------------------
__global__ __launch_bounds__(H3_, 1)
void gru_scan_r4(const float* __restrict__ xp,            // [2][NL][576]
                 const unsigned int* __restrict__ Wpf,    // [24][576][4] f16-pairs
                 const unsigned int* __restrict__ Wpb,
                 const float* __restrict__ bhf,
                 const float* __restrict__ bhb,
                 float* __restrict__ hcat) {              // [NL][384]
  const int dir = blockIdx.x >> 4;
  const int n   = blockIdx.x & 15;
  const float* __restrict__ xpd = xp + ((size_t)dir * NL_ + (size_t)n * L_) * H3_;
  const unsigned int* __restrict__ Wp = dir ? Wpb : Wpf;
  const float* __restrict__ bh  = dir ? bhb : bhf;
  float* __restrict__ outd = hcat + (size_t)n * L_ * IN1_ + dir * H_;

  const int j = threadIdx.x;   // 0..575

  __shared__ __align__(16) unsigned int h16[128];  // 96 used (192 f16), padded
  __shared__ float gh_lds[H3_];
  __shared__ float xn_lds[H_];

  uint4 w[24];
  #pragma unroll
  for (int kc = 0; kc < 24; ++kc)
    w[kc] = ((const uint4*)Wp)[kc * H3_ + j];

  const float bj = bh[j];
  if (j < 128) h16[j] = 0u;
  float hprev = 0.f;                       // valid for j < H_
  __syncthreads();

  const uint4* __restrict__ h4 = (const uint4*)h16;
  const int ts = dir ? -1 : 1;
  int t = dir ? (L_ - 1) : 0;
  float xv = xpd[(size_t)t * H3_ + j];     // prefetched current step

  for (int tt = 0; tt < L_; ++tt) {
    float xvn = 0.f;
    if (tt + 1 < L_) xvn = xpd[(size_t)(t + ts) * H3_ + j];

    float a0 = bj, a1 = 0.f, a2 = 0.f, a3 = 0.f;
    #pragma unroll
    for (int kc = 0; kc < 24; ++kc) {
      uint4 hv = h4[kc];                   // broadcast: same addr across wave
      a0 = dot2acc(w[kc].x, hv.x, a0);
      a1 = dot2acc(w[kc].y, hv.y, a1);
      a2 = dot2acc(w[kc].z, hv.z, a2);
      a3 = dot2acc(w[kc].w, hv.w, a3);
    }
    float acc = (a0 + a1) + (a2 + a3);

    if (j < 2 * H_) acc += xv;
    gh_lds[j] = acc;
    if (j >= 2 * H_) xn_lds[j - 2 * H_] = xv;
    __syncthreads();

    if (j < H_) {
      const float r  = 1.f / (1.f + __expf(-gh_lds[j]));
      const float z  = 1.f / (1.f + __expf(-gh_lds[H_ + j]));
      const float nn = tanhf(xn_lds[j] + r * gh_lds[2 * H_ + j]);
      const float hnew = (1.f - z) * nn + z * hprev;
      hprev = hnew;
      H16U cv; cv.f = (_Float16)hnew;
      ((unsigned short*)h16)[j] = cv.s;    // ds_write_b16
      outd[(size_t)t * IN1_ + j] = hnew;
    }
    __syncthreads();

    xv = xvn;
    t += ts;
  }
}

// ---------------- K6: fused per-channel FFN + LayerNorm + ReLU + Linear ----
__global__ __launch_bounds__(256)
void ffn_kernel(const float* __restrict__ hcat, const float* __restrict__ adm_out,
                const float* __restrict__ W1, const float* __restrict__ b1,
                const float* __restrict__ lng, const float* __restrict__ lnb,
                const float* __restrict__ W2, const float* __restrict__ b2,
                float* __restrict__ out) {
  constexpr int FROWS = 8;
  const int d = blockIdx.y;            // 12
  const int row_base = blockIdx.x * 128;
  const int t = threadIdx.x;
  const int lane = t & 63, w = t >> 6;

  __shared__ __align__(16) float featL[FROWS][48];
  __shared__ __align__(16) float hhL[FROWS][FFH_];
  __shared__ float gL[FFH_], bLn[FFH_], w2L[FFH_], b1L[FFH_];

  for (int i = t; i < FFH_; i += 256) {
    gL[i]  = lng[d * FFH_ + i];
    bLn[i] = lnb[d * FFH_ + i];
    w2L[i] = W2[d * FFH_ + i];
    b1L[i] = b1[d * FFH_ + i];
  }
  float w1a[48], w1b[48];
  {
    const float* ra = W1 + ((size_t)d * FFH_ + t) * 48;
    const float* rb = W1 + ((size_t)d * FFH_ + 256 + t) * 48;
    #pragma unroll
    for (int kc = 0; kc < 12; ++kc) {
      float4 va = F4(ra + kc * 4);
      w1a[4*kc+0]=va.x; w1a[4*kc+1]=va.y; w1a[4*kc+2]=va.z; w1a[4*kc+3]=va.w;
      float4 vb = F4(rb + kc * 4);
      w1b[4*kc+0]=vb.x; w1b[4*kc+1]=vb.y; w1b[4*kc+2]=vb.z; w1b[4*kc+3]=vb.w;
    }
  }
  const float b2v = b2[d];
  __syncthreads();

  for (int c0 = 0; c0 < 128; c0 += FROWS) {
    for (int idx = t; idx < FROWS * 48; idx += 256) {
      const int r = idx / 48, k = idx % 48;
      const int row = row_base + c0 + r;
      float v;
      if (k < 32) v = hcat[(size_t)row * IN1_ + d * 32 + k];
      else        v = adm_out[(row >> 10) * HID_ + (k - 32)];
      featL[r][k] = v;
    }
    __syncthreads();
    float acc_a[FROWS] = {}, acc_b[FROWS] = {};
    #pragma unroll
    for (int r = 0; r < FROWS; ++r) {
      const float4* f4 = (const float4*)featL[r];
      #pragma unroll
      for (int kc = 0; kc < 12; ++kc) {
        float4 f = f4[kc];
        acc_a[r] = fmaf(w1a[4*kc+0], f.x, acc_a[r]);
        acc_a[r] = fmaf(w1a[4*kc+1], f.y, acc_a[r]);
        acc_a[r] = fmaf(w1a[4*kc+2], f.z, acc_a[r]);
        acc_a[r] = fmaf(w1a[4*kc+3], f.w, acc_a[r]);
        acc_b[r] = fmaf(w1b[4*kc+0], f.x, acc_b[r]);
        acc_b[r] = fmaf(w1b[4*kc+1], f.y, acc_b[r]);
        acc_b[r] = fmaf(w1b[4*kc+2], f.z, acc_b[r]);
        acc_b[r] = fmaf(w1b[4*kc+3], f.w, acc_b[r]);
      }
    }
    #pragma unroll
    for (int r = 0; r < FROWS; ++r) {
      hhL[r][t]       = acc_a[r] + b1L[t];
      hhL[r][t + 256] = acc_b[r] + b1L[t + 256];
    }
    __syncthreads();
    #pragma unroll
    for (int rr = 0; rr < 2; ++rr) {
      const int r = w + rr * 4;
      const float4* h4 = (const float4*)hhL[r];
      float4 x0 = h4[lane * 2], x1 = h4[lane * 2 + 1];
      float s = x0.x + x0.y + x0.z + x0.w + x1.x + x1.y + x1.z + x1.w;
      float q = x0.x*x0.x + x0.y*x0.y + x0.z*x0.z + x0.w*x0.w
              + x1.x*x1.x + x1.y*x1.y + x1.z*x1.z + x1.w*x1.w;
      #pragma unroll
      for (int m = 1; m < 64; m <<= 1) { s += __shfl_xor(s, m); q += __shfl_xor(q, m); }
      const float mu   = s * (1.f / FFH_);
      const float var  = q * (1.f / FFH_) - mu * mu;
      const float rstd = rsqrtf(var + 1e-5f);
      const int col = lane * 8;
      const float xs[8] = {x0.x, x0.y, x0.z, x0.w, x1.x, x1.y, x1.z, x1.w};
      float o = 0.f;
      #pragma unroll
      for (int i = 0; i < 8; ++i) {
        float v = (xs[i] - mu) * rstd * gL[col + i] + bLn[col + i];
        v = fmaxf(v, 0.f);
        o = fmaf(v, w2L[col + i], o);
      }
      #pragma unroll
      for (int m = 1; m < 64; m <<= 1) o += __shfl_xor(o, m);
      if (lane == 0) {
        const int row = row_base + c0 + r;
        out[(size_t)row * D_ + d] = o + b2v;
      }
    }
    __syncthreads();
  }
}

// ---------------------------------------------------------------------------
extern "C" void kernel_launch(void* const* d_in, const int* in_sizes, int n_in,
                              void* d_out, int out_size, void* d_ws, size_t ws_size,
                              hipStream_t stream) {
  const float* series = (const float*)d_in[0];
  const float* adm    = (const float*)d_in[1];
  const int*   mask   = (const int*)  d_in[2];
  const float* sW     = (const float*)d_in[3];
  const float* membW  = (const float*)d_in[4];
  const float* aW1    = (const float*)d_in[5];
  const float* ab1    = (const float*)d_in[6];
  const float* aW2    = (const float*)d_in[7];
  const float* ab2    = (const float*)d_in[8];
  const float* Wih0f  = (const float*)d_in[9];
  const float* Whh0f  = (const float*)d_in[10];
  const float* bih0f  = (const float*)d_in[11];
  const float* bhh0f  = (const float*)d_in[12];
  const float* Wih0b  = (const float*)d_in[13];
  const float* Whh0b  = (const float*)d_in[14];
  const float* bih0b  = (const float*)d_in[15];
  const float* bhh0b  = (const float*)d_in[16];
  const float* Wih1f  = (const float*)d_in[17];
  const float* Whh1f  = (const float*)d_in[18];
  const float* bih1f  = (const float*)d_in[19];
  const float* bhh1f  = (const float*)d_in[20];
  const float* Wih1b  = (const float*)d_in[21];
  const float* Whh1b  = (const float*)d_in[22];
  const float* bih1b  = (const float*)d_in[23];
  const float* bhh1b  = (const float*)d_in[24];
  const float* ffnW1  = (const float*)d_in[25];
  const float* ffnb1  = (const float*)d_in[26];
  const float* lng    = (const float*)d_in[27];
  const float* lnb    = (const float*)d_in[28];
  const float* ffnW2  = (const float*)d_in[29];
  const float* ffnb2  = (const float*)d_in[30];
  float* outp = (float*)d_out;

  // workspace layout (floats)
  float* ws      = (float*)d_ws;
  float* adm_out = ws;                                   // 256
  float* emb     = adm_out + 256;                        // NL*96
  float* xp      = emb + (size_t)NL_ * IN0_;             // 2*NL*576
  float* hcat    = xp + (size_t)2 * NL_ * H3_;           // NL*384
  unsigned int* wmf0f = (unsigned int*)(hcat + (size_t)NL_ * IN1_);  // 55,296 u32 each
  unsigned int* wmf0b = wmf0f + (size_t)H3_ * 96;
  unsigned int* wp1f  = wmf0b + (size_t)H3_ * 96;
  unsigned int* wp1b  = wp1f + (size_t)H3_ * 96;

  adm_mlp_kernel<<<1, 256, 0, stream>>>(adm, aW1, ab1, aW2, ab2, adm_out);
  embed_kernel<<<(NL_ * IN0_) / 256, 256, 0, stream>>>(series, mask, sW, membW, emb);
  wmf_pack16_kernel<<<(216 * 256) / 256, 256, 0, stream>>>(Whh0f, wmf0f);
  wmf_pack16_kernel<<<(216 * 256) / 256, 256, 0, stream>>>(Whh0b, wmf0b);
  whh_pack16_kernel<<<(H3_ * 96) / 256, 256, 0, stream>>>(Whh1f, wp1f);
  whh_pack16_kernel<<<(H3_ * 96) / 256, 256, 0, stream>>>(Whh1b, wp1b);

  // layer 0 — MFMA scan (A-side)
  xp_gemm_kernel<<<dim3(NL_ / 128, (2 * H3_) / 128), 256, 0, stream>>>(
      emb, IN0_, Wih0f, Wih0b, bih0f, bih0b, xp);
  gru_scan_mf<<<8, 512, 0, stream>>>(xp, wmf0f, wmf0b, bhh0f, bhh0b, hcat);

  // layer 1 — exact-R4 control (B-side)
  xp_gemm_kernel<<<dim3(NL_ / 128, (2 * H3_) / 128), 256, 0, stream>>>(
      hcat, IN1_, Wih1f, Wih1b, bih1f, bih1b, xp);
  gru_scan_r4<<<32, H3_, 0, stream>>>(xp, wp1f, wp1b, bhh1f, bhh1b, hcat);

  // fused FFN
  ffn_kernel<<<dim3(NL_ / 128, D_), 256, 0, stream>>>(
      hcat, adm_out, ffnW1, ffnb1, lng, lnb, ffnW2, ffnb2, outp);
}